// Round 10
// baseline (1324.210 us; speedup 1.0000x reference)
//
#include <hip/hip_runtime.h>

#define NN 100000
#define NE 1600000
#define NTILE 3125           // NN/32; tile = dst >> 5
#define NSL 13               // src slices: slice = src >> 13
#define NBUCK (NTILE * NSL)
#define GRID_SC 159          // ceil(NBUCK/256)
#define SRC_MASK 0x1FFFF
#define PROBE_TILES 500

__device__ __forceinline__ float rdlane(float v, int i) {
    return __uint_as_float(__builtin_amdgcn_readlane(__float_as_uint(v), (unsigned)i));
}

// ===================== build (identical to R9) =====================
__global__ __launch_bounds__(256) void hist_k(const int* __restrict__ ei,
                                              int* __restrict__ cnt) {
    int e = blockIdx.x * 256 + threadIdx.x;
    int src = ei[e];
    int dst = ei[NE + e];
    atomicAdd(&cnt[(dst >> 5) * NSL + (src >> 13)], 1);
}

__global__ __launch_bounds__(256) void scanA_k(const int* __restrict__ in,
                                               int* __restrict__ scanned,
                                               int* __restrict__ bsums, int n) {
    __shared__ int tmp[256];
    int i = blockIdx.x * 256 + threadIdx.x;
    int v = (i < n) ? in[i] : 0;
    tmp[threadIdx.x] = v;
    __syncthreads();
#pragma unroll
    for (int off = 1; off < 256; off <<= 1) {
        int t = (threadIdx.x >= off) ? tmp[threadIdx.x - off] : 0;
        __syncthreads();
        tmp[threadIdx.x] += t;
        __syncthreads();
    }
    if (i < n) scanned[i] = tmp[threadIdx.x];
    if (threadIdx.x == 255) bsums[blockIdx.x] = tmp[255];
}

__global__ __launch_bounds__(256) void scanB_k(int* __restrict__ b, int n) {
    __shared__ int tmp[256];
    int t = threadIdx.x;
    tmp[t] = (t < n) ? b[t] : 0;
    __syncthreads();
#pragma unroll
    for (int off = 1; off < 256; off <<= 1) {
        int u = (t >= off) ? tmp[t - off] : 0;
        __syncthreads();
        tmp[t] += u;
        __syncthreads();
    }
    if (t < n) b[t] = tmp[t];
}

__global__ __launch_bounds__(256) void combine_k(const int* __restrict__ S0,
                                                 const int* __restrict__ B0,
                                                 const int* __restrict__ cnt,
                                                 int* __restrict__ Q,
                                                 int* __restrict__ cursor) {
    int i = blockIdx.x * 256 + threadIdx.x;
    if (i < NBUCK) {
        int c0 = i >> 8;
        int excl = S0[i] - cnt[i] + (c0 ? B0[c0 - 1] : 0);
        Q[i] = excl;
        cursor[i] = excl;
    }
    if (i == NBUCK) Q[i] = NE;
}

__global__ __launch_bounds__(256) void fill_k(const int* __restrict__ ei,
                                              int* __restrict__ cursor,
                                              int* __restrict__ packed) {
    int e = blockIdx.x * 256 + threadIdx.x;
    int src = ei[e];
    int dst = ei[NE + e];
    int pos = atomicAdd(&cursor[(dst >> 5) * NSL + (src >> 13)], 1);
    packed[pos] = ((dst & 31) << 17) | src;
}

// ===================== layer-1 edge phase -> agg1 =====================
__global__ __launch_bounds__(256) void g1_edge(const float* __restrict__ x,
                                               const int* __restrict__ Q,
                                               const int* __restrict__ packed,
                                               float* __restrict__ agg1) {
    __shared__ float A[32 * 32];
    for (int i = threadIdx.x; i < 32 * 32; i += 256) A[i] = 0.f;
    __syncthreads();

    int tile = blockIdx.x;
    int lane = threadIdx.x & 63;
    int w = threadIdx.x >> 6;
    int c = lane & 31;
    int p = lane >> 5;
    int e0 = Q[tile * NSL], e1 = Q[tile * NSL + NSL];

    int e = e0 + 2 * w + p;
    for (; e + 24 < e1; e += 32) {
        int pk0 = packed[e], pk1 = packed[e + 8];
        int pk2 = packed[e + 16], pk3 = packed[e + 24];
        float v0 = x[(size_t)(pk0 & SRC_MASK) * 32 + c];
        float v1 = x[(size_t)(pk1 & SRC_MASK) * 32 + c];
        float v2 = x[(size_t)(pk2 & SRC_MASK) * 32 + c];
        float v3 = x[(size_t)(pk3 & SRC_MASK) * 32 + c];
        atomicAdd(&A[(pk0 >> 17) * 32 + c], v0);
        atomicAdd(&A[(pk1 >> 17) * 32 + c], v1);
        atomicAdd(&A[(pk2 >> 17) * 32 + c], v2);
        atomicAdd(&A[(pk3 >> 17) * 32 + c], v3);
    }
    for (; e < e1; e += 8) {
        int pk = packed[e];
        atomicAdd(&A[(pk >> 17) * 32 + c], x[(size_t)(pk & SRC_MASK) * 32 + c]);
    }
    __syncthreads();
    for (int i = threadIdx.x; i < 32 * 32; i += 256)
        agg1[(size_t)tile * 1024 + i] = A[i];
}

// ===================== layer-1 MLP: agg1 + x -> h =====================
__global__ __launch_bounds__(256) void m1_mlp(const float* __restrict__ x,
                                              const float* __restrict__ agg1,
                                              const float* __restrict__ W1,
                                              const float* __restrict__ b1,
                                              const float* __restrict__ W2,
                                              const float* __restrict__ b2,
                                              float* __restrict__ h) {
    int tile = blockIdx.x;
    int lane = threadIdx.x & 63;
    int w = threadIdx.x >> 6;
    int c = lane & 31;
    int rbase = w * 8;
    int nodeb = tile * 32 + rbase;

    float aval[8], hid[8], o[8];
#pragma unroll
    for (int k = 0; k < 8; ++k)
        aval[k] = agg1[(size_t)(nodeb + k) * 32 + c] + x[(size_t)(nodeb + k) * 32 + c];

    float bb1 = b1[lane];
#pragma unroll
    for (int k = 0; k < 8; ++k) hid[k] = bb1;
    for (int i = 0; i < 32; ++i) {
        float wv = W1[i * 64 + lane];
#pragma unroll
        for (int k = 0; k < 8; ++k)
            hid[k] = fmaf(rdlane(aval[k], i), wv, hid[k]);
    }
#pragma unroll
    for (int k = 0; k < 8; ++k) hid[k] = fmaxf(hid[k], 0.f);

    float bb2 = b2[lane];
#pragma unroll
    for (int k = 0; k < 8; ++k) o[k] = bb2;
    for (int j = 0; j < 64; ++j) {
        float wv = W2[j * 64 + lane];
#pragma unroll
        for (int k = 0; k < 8; ++k)
            o[k] = fmaf(rdlane(hid[k], j), wv, o[k]);
    }
#pragma unroll
    for (int k = 0; k < 8; ++k)
        h[(size_t)(nodeb + k) * 64 + lane] = fmaxf(o[k], 0.f);
}

// ===================== layer-2 edge phase -> agg2 =====================
__global__ __launch_bounds__(256) void g2_edge(const float* __restrict__ h,
                                               const int* __restrict__ Q,
                                               const int* __restrict__ packed,
                                               float* __restrict__ agg2) {
    __shared__ float A[32 * 64];
    for (int i = threadIdx.x; i < 32 * 64; i += 256) A[i] = 0.f;
    __syncthreads();

    int tile = blockIdx.x;
    int lane = threadIdx.x & 63;
    int w = threadIdx.x >> 6;
    int e0 = Q[tile * NSL], e1 = Q[tile * NSL + NSL];

    int e = e0 + w;
    for (; e + 12 < e1; e += 16) {
        int pk0 = packed[e], pk1 = packed[e + 4];
        int pk2 = packed[e + 8], pk3 = packed[e + 12];
        float v0 = h[(size_t)(pk0 & SRC_MASK) * 64 + lane];
        float v1 = h[(size_t)(pk1 & SRC_MASK) * 64 + lane];
        float v2 = h[(size_t)(pk2 & SRC_MASK) * 64 + lane];
        float v3 = h[(size_t)(pk3 & SRC_MASK) * 64 + lane];
        atomicAdd(&A[(pk0 >> 17) * 64 + lane], v0);
        atomicAdd(&A[(pk1 >> 17) * 64 + lane], v1);
        atomicAdd(&A[(pk2 >> 17) * 64 + lane], v2);
        atomicAdd(&A[(pk3 >> 17) * 64 + lane], v3);
    }
    for (; e < e1; e += 4) {
        int pk = packed[e];
        atomicAdd(&A[(pk >> 17) * 64 + lane],
                  h[(size_t)(pk & SRC_MASK) * 64 + lane]);
    }
    __syncthreads();
    for (int i = threadIdx.x; i < 32 * 64; i += 256)
        agg2[(size_t)tile * 2048 + i] = A[i];
}

// ===================== layer-2 MLP: agg2 + h -> out =====================
__global__ __launch_bounds__(256) void m2_mlp(const float* __restrict__ h,
                                              const float* __restrict__ agg2,
                                              const float* __restrict__ W3,
                                              const float* __restrict__ b3,
                                              const float* __restrict__ W4,
                                              const float* __restrict__ b4,
                                              float* __restrict__ out) {
    int tile = blockIdx.x;
    int lane = threadIdx.x & 63;
    int w = threadIdx.x >> 6;
    int rbase = w * 8;
    int nodeb = tile * 32 + rbase;

    float aval[8], hid[8], o[8];
#pragma unroll
    for (int k = 0; k < 8; ++k)
        aval[k] = agg2[(size_t)(nodeb + k) * 64 + lane] + h[(size_t)(nodeb + k) * 64 + lane];

    float bb3 = b3[lane];
#pragma unroll
    for (int k = 0; k < 8; ++k) hid[k] = bb3;
    for (int i = 0; i < 64; ++i) {
        float wv = W3[i * 64 + lane];
#pragma unroll
        for (int k = 0; k < 8; ++k)
            hid[k] = fmaf(rdlane(aval[k], i), wv, hid[k]);
    }
#pragma unroll
    for (int k = 0; k < 8; ++k) hid[k] = fmaxf(hid[k], 0.f);

    float bb4 = b4[lane & 31];
#pragma unroll
    for (int k = 0; k < 8; ++k) o[k] = bb4;
    for (int j = 0; j < 64; ++j) {
        float wv = W4[j * 32 + (lane & 31)];
#pragma unroll
        for (int k = 0; k < 8; ++k)
            o[k] = fmaf(rdlane(hid[k], j), wv, o[k]);
    }
    if (lane < 32) {
#pragma unroll
        for (int k = 0; k < 8; ++k)
            out[(size_t)(nodeb + k) * 32 + lane] = o[k];
    }
}

// ============ PROBE 1: identical instructions, sequential src (dead output) ============
__global__ __launch_bounds__(256) void p_seq(const float* __restrict__ h,
                                             const int* __restrict__ Q,
                                             const int* __restrict__ packed,
                                             float* __restrict__ scratch) {
    __shared__ float A[32 * 64];
    for (int i = threadIdx.x; i < 32 * 64; i += 256) A[i] = 0.f;
    __syncthreads();

    int tile = blockIdx.x;
    int lane = threadIdx.x & 63;
    int w = threadIdx.x >> 6;
    int e0 = Q[tile * NSL], e1 = Q[tile * NSL + NSL];

    int e = e0 + w;
    for (; e + 12 < e1; e += 16) {
        int pk0 = packed[e], pk1 = packed[e + 4];
        int pk2 = packed[e + 8], pk3 = packed[e + 12];
        // sequential-ish rows, pk kept live via low bit
        int s0 = (e ^ (pk0 & 1)) & 8191;
        int s1 = ((e + 4) ^ (pk1 & 1)) & 8191;
        int s2 = ((e + 8) ^ (pk2 & 1)) & 8191;
        int s3 = ((e + 12) ^ (pk3 & 1)) & 8191;
        float v0 = h[(size_t)s0 * 64 + lane];
        float v1 = h[(size_t)s1 * 64 + lane];
        float v2 = h[(size_t)s2 * 64 + lane];
        float v3 = h[(size_t)s3 * 64 + lane];
        atomicAdd(&A[(pk0 >> 17) * 64 + lane], v0);
        atomicAdd(&A[(pk1 >> 17) * 64 + lane], v1);
        atomicAdd(&A[(pk2 >> 17) * 64 + lane], v2);
        atomicAdd(&A[(pk3 >> 17) * 64 + lane], v3);
    }
    for (; e < e1; e += 4) {
        int pk = packed[e];
        int s = (e ^ (pk & 1)) & 8191;
        atomicAdd(&A[(pk >> 17) * 64 + lane], h[(size_t)s * 64 + lane]);
    }
    __syncthreads();
    for (int i = threadIdx.x; i < 32 * 64; i += 256)
        scratch[(size_t)tile * 2048 + i] = A[i];
}

// ============ PROBE 2: float4 lanes — 4 edges per VMEM instruction (dead output) ============
__global__ __launch_bounds__(256) void p_f4(const float4* __restrict__ h4,
                                            const int* __restrict__ Q,
                                            const int* __restrict__ packed,
                                            float* __restrict__ scratch) {
    __shared__ float A[32 * 64];
    for (int i = threadIdx.x; i < 32 * 64; i += 256) A[i] = 0.f;
    __syncthreads();

    int tile = blockIdx.x;
    int lane = threadIdx.x & 63;
    int w = threadIdx.x >> 6;
    int cp = lane & 15;        // channel quad: ch 4cp..4cp+3
    int g = lane >> 4;         // edge sub-slot 0..3
    int e0 = Q[tile * NSL], e1 = Q[tile * NSL + NSL];

    int e = e0 + 4 * w;        // wave covers 4 edges per step, block covers 16
    for (; e + 3 < e1; e += 16) {
        int pk = packed[e + g];
        float4 v = h4[(size_t)(pk & SRC_MASK) * 16 + cp];
        int row = pk >> 17;
        atomicAdd(&A[row * 64 + cp * 4 + 0], v.x);
        atomicAdd(&A[row * 64 + cp * 4 + 1], v.y);
        atomicAdd(&A[row * 64 + cp * 4 + 2], v.z);
        atomicAdd(&A[row * 64 + cp * 4 + 3], v.w);
    }
    for (; e < e1; e += 16) {
        int ee = e + g;
        if (ee < e1) {
            int pk = packed[ee];
            float4 v = h4[(size_t)(pk & SRC_MASK) * 16 + cp];
            int row = pk >> 17;
            atomicAdd(&A[row * 64 + cp * 4 + 0], v.x);
            atomicAdd(&A[row * 64 + cp * 4 + 1], v.y);
            atomicAdd(&A[row * 64 + cp * 4 + 2], v.z);
            atomicAdd(&A[row * 64 + cp * 4 + 3], v.w);
        }
    }
    __syncthreads();
    for (int i = threadIdx.x; i < 32 * 64; i += 256)
        scratch[(size_t)tile * 2048 + i] = A[i];
}

extern "C" void kernel_launch(void* const* d_in, const int* in_sizes, int n_in,
                              void* d_out, int out_size, void* d_ws, size_t ws_size,
                              hipStream_t stream) {
    const float* x  = (const float*)d_in[0];
    const int*   ei = (const int*)d_in[1];
    const float* W1 = (const float*)d_in[2];
    const float* b1 = (const float*)d_in[3];
    const float* W2 = (const float*)d_in[4];
    const float* b2 = (const float*)d_in[5];
    const float* W3 = (const float*)d_in[6];
    const float* b3 = (const float*)d_in[7];
    const float* W4 = (const float*)d_in[8];
    const float* b4 = (const float*)d_in[9];
    float* out = (float*)d_out;

    char* ws = (char*)d_ws;
    float* h      = (float*)ws;               ws += (size_t)NN * 64 * 4;       // 25.6 MB
    int*   packed = (int*)ws;                 ws += (size_t)NE * 4;            // 6.4 MB
    int*   Q      = (int*)ws;                 ws += (size_t)(NBUCK + 1) * 4;   // 163 KB
    float* agg1   = (float*)ws;               ws += (size_t)NN * 32 * 4;       // 12.8 MB
    float* agg2   = (float*)ws;               ws += (size_t)NN * 64 * 4;       // 25.6 MB

    // build-time arrays overlay the h region (dead before g1_edge runs)
    char* ov = (char*)h;
    int* cnt    = (int*)ov;                   ov += (size_t)NBUCK * 4;
    int* S0     = (int*)ov;                   ov += (size_t)NBUCK * 4;
    int* cursor = (int*)ov;                   ov += (size_t)NBUCK * 4;
    int* B0     = (int*)ov;                   ov += (size_t)GRID_SC * 4;

    // ---- build ----
    hipMemsetAsync(cnt, 0, (size_t)NBUCK * 4, stream);
    hist_k<<<NE / 256, 256, 0, stream>>>(ei, cnt);
    scanA_k<<<GRID_SC, 256, 0, stream>>>(cnt, S0, B0, NBUCK);
    scanB_k<<<1, 256, 0, stream>>>(B0, GRID_SC);
    combine_k<<<GRID_SC, 256, 0, stream>>>(S0, B0, cnt, Q, cursor);
    fill_k<<<NE / 256, 256, 0, stream>>>(ei, cursor, packed);

    // ---- layer 1 (split) ----
    g1_edge<<<NTILE, 256, 0, stream>>>(x, Q, packed, agg1);
    m1_mlp<<<NTILE, 256, 0, stream>>>(x, agg1, W1, b1, W2, b2, h);

    // ---- layer 2 (split) ----
    g2_edge<<<NTILE, 256, 0, stream>>>(h, Q, packed, agg2);
    m2_mlp<<<NTILE, 256, 0, stream>>>(h, agg2, W3, b3, W4, b4, out);

    // ---- probes on a 500-tile prefix, writing dead scratch (agg1 region) ----
    p_seq<<<PROBE_TILES, 256, 0, stream>>>(h, Q, packed, agg1);
    p_f4<<<PROBE_TILES, 256, 0, stream>>>((const float4*)h, Q, packed, agg1);
}

// Round 11
// 610.188 us; speedup vs baseline: 2.1702x; 2.1702x over previous
//
#include <hip/hip_runtime.h>

#define NN 100000
#define NE 1600000
#define NB 391        // ceil(NN/256)
#define NS 13         // src slices: slice = src >> 13
#define NSP1 14
#define SLICE_SHIFT 13

// ============== build: per-(dst,slice) bucketed CSR (R5's, proven FETCH win) ==============

__global__ __launch_bounds__(256) void hist2_k(const int* __restrict__ ei,
                                               int* __restrict__ deg2) {
    int e = blockIdx.x * 256 + threadIdx.x;
    int src = ei[e];
    int dst = ei[NE + e];
    atomicAdd(&deg2[dst * NS + (src >> SLICE_SHIFT)], 1);
}

__global__ __launch_bounds__(256) void rowsum_k(const int* __restrict__ deg2,
                                                int* __restrict__ deg) {
    int i = blockIdx.x * 256 + threadIdx.x;
    if (i < NN) {
        int s = 0;
#pragma unroll
        for (int k = 0; k < NS; ++k) s += deg2[i * NS + k];
        deg[i] = s;
    }
}

__global__ __launch_bounds__(256) void scan1_k(const int* __restrict__ deg,
                                               int* __restrict__ scanned,
                                               int* __restrict__ bsums) {
    __shared__ int tmp[256];
    int i = blockIdx.x * 256 + threadIdx.x;
    int v = (i < NN) ? deg[i] : 0;
    tmp[threadIdx.x] = v;
    __syncthreads();
#pragma unroll
    for (int off = 1; off < 256; off <<= 1) {
        int t = (threadIdx.x >= off) ? tmp[threadIdx.x - off] : 0;
        __syncthreads();
        tmp[threadIdx.x] += t;
        __syncthreads();
    }
    if (i < NN) scanned[i] = tmp[threadIdx.x];
    if (threadIdx.x == 255) bsums[blockIdx.x] = tmp[255];
}

__global__ __launch_bounds__(512) void scan2_k(int* __restrict__ bsums) {
    __shared__ int tmp[512];
    int v = (threadIdx.x < NB) ? bsums[threadIdx.x] : 0;
    tmp[threadIdx.x] = v;
    __syncthreads();
#pragma unroll
    for (int off = 1; off < 512; off <<= 1) {
        int t = (threadIdx.x >= off) ? tmp[threadIdx.x - off] : 0;
        __syncthreads();
        tmp[threadIdx.x] += t;
        __syncthreads();
    }
    if (threadIdx.x < NB) bsums[threadIdx.x] = tmp[threadIdx.x];
}

// P[n][0] = row start (stable); P[n][s+1] = bucket-s cursor (start before fill,
// end after fill). Flat row = [P[n][0], P[n][13]) after fill, slice-ordered.
__global__ __launch_bounds__(256) void scan3b_k(const int* __restrict__ scanned,
                                                const int* __restrict__ bsums,
                                                const int* __restrict__ deg,
                                                const int* __restrict__ deg2,
                                                int* __restrict__ P) {
    int i = blockIdx.x * 256 + threadIdx.x;
    if (i < NN) {
        int incl = scanned[i] + (blockIdx.x ? bsums[blockIdx.x - 1] : 0);
        int run = incl - deg[i];
        P[i * NSP1 + 0] = run;
#pragma unroll
        for (int s = 0; s < NS; ++s) {
            P[i * NSP1 + s + 1] = run;
            run += deg2[i * NS + s];
        }
    }
}

__global__ __launch_bounds__(256) void fill2_k(const int* __restrict__ ei,
                                               int* __restrict__ P,
                                               int* __restrict__ col) {
    int e = blockIdx.x * 256 + threadIdx.x;
    int src = ei[e];
    int dst = ei[NE + e];
    int pos = atomicAdd(&P[dst * NSP1 + (src >> SLICE_SHIFT) + 1], 1);
    col[pos] = src;
}

// ============ layer 1: reg-ILP gather(x, slice-sorted) + MLP1 -> h ============
// one wave per node; lanes 0-31 / 32-63 take alternate edges; 4-deep per parity.
__global__ __launch_bounds__(256) void fused1(const float* __restrict__ x,
                                              const int* __restrict__ P,
                                              const int* __restrict__ col,
                                              const float* __restrict__ W1,
                                              const float* __restrict__ b1,
                                              const float* __restrict__ W2,
                                              const float* __restrict__ b2,
                                              float* __restrict__ h) {
    __shared__ float W1s[32 * 64];
    __shared__ float W2s[64 * 64];
    __shared__ float b1s[64];
    __shared__ float b2s[64];
    for (int i = threadIdx.x; i < 32 * 64; i += 256) W1s[i] = W1[i];
    for (int i = threadIdx.x; i < 64 * 64; i += 256) W2s[i] = W2[i];
    if (threadIdx.x < 64) {
        b1s[threadIdx.x] = b1[threadIdx.x];
        b2s[threadIdx.x] = b2[threadIdx.x];
    }
    __syncthreads();

    int lane = threadIdx.x & 63;
    int c = lane & 31;
    int p = lane >> 5;
    int gw = blockIdx.x * 4 + (threadIdx.x >> 6);
    int nwaves = gridDim.x * 4;

    for (int node = gw; node < NN; node += nwaves) {
        int s0 = P[node * NSP1];
        int s1 = P[node * NSP1 + NS];
        float self = x[(size_t)node * 32 + c];

        float a0 = 0.f, a1 = 0.f, a2 = 0.f, a3 = 0.f;
        int e = s0 + p;
        for (; e + 6 < s1; e += 8) {
            int c0 = col[e], c1 = col[e + 2], c2 = col[e + 4], c3 = col[e + 6];
            a0 += x[(size_t)c0 * 32 + c];
            a1 += x[(size_t)c1 * 32 + c];
            a2 += x[(size_t)c2 * 32 + c];
            a3 += x[(size_t)c3 * 32 + c];
        }
        for (; e < s1; e += 2)
            a0 += x[(size_t)col[e] * 32 + c];
        float acc = (a0 + a1) + (a2 + a3);
        acc += __shfl_xor(acc, 32);
        float aval = acc + self;

        float s = b1s[lane];
#pragma unroll
        for (int i = 0; i < 32; ++i)
            s += __shfl(aval, i) * W1s[i * 64 + lane];
        float t = fmaxf(s, 0.f);

        float s2 = b2s[lane];
#pragma unroll
        for (int j = 0; j < 64; ++j)
            s2 += __shfl(t, j) * W2s[j * 64 + lane];
        h[(size_t)node * 64 + lane] = fmaxf(s2, 0.f);
    }
}

// ============ layer 2: reg-ILP gather(h, slice-sorted) + MLP2 -> out ============
// one wave per node; 8 independent accumulators = 8 loads in flight.
__global__ __launch_bounds__(256) void fused2(const float* __restrict__ h,
                                              const int* __restrict__ P,
                                              const int* __restrict__ col,
                                              const float* __restrict__ W3,
                                              const float* __restrict__ b3,
                                              const float* __restrict__ W4,
                                              const float* __restrict__ b4,
                                              float* __restrict__ out) {
    __shared__ float W3s[64 * 64];
    __shared__ float W4s[64 * 32];
    __shared__ float b3s[64];
    __shared__ float b4s[32];
    for (int i = threadIdx.x; i < 64 * 64; i += 256) W3s[i] = W3[i];
    for (int i = threadIdx.x; i < 64 * 32; i += 256) W4s[i] = W4[i];
    if (threadIdx.x < 64) b3s[threadIdx.x] = b3[threadIdx.x];
    if (threadIdx.x < 32) b4s[threadIdx.x] = b4[threadIdx.x];
    __syncthreads();

    int lane = threadIdx.x & 63;
    int gw = blockIdx.x * 4 + (threadIdx.x >> 6);
    int nwaves = gridDim.x * 4;

    for (int node = gw; node < NN; node += nwaves) {
        int s0 = P[node * NSP1];
        int s1 = P[node * NSP1 + NS];
        float self = h[(size_t)node * 64 + lane];

        float a0 = 0.f, a1 = 0.f, a2 = 0.f, a3 = 0.f;
        float a4 = 0.f, a5 = 0.f, a6 = 0.f, a7 = 0.f;
        int e = s0;
        for (; e + 7 < s1; e += 8) {
            int c0 = col[e],     c1 = col[e + 1], c2 = col[e + 2], c3 = col[e + 3];
            int c4 = col[e + 4], c5 = col[e + 5], c6 = col[e + 6], c7 = col[e + 7];
            a0 += h[(size_t)c0 * 64 + lane];
            a1 += h[(size_t)c1 * 64 + lane];
            a2 += h[(size_t)c2 * 64 + lane];
            a3 += h[(size_t)c3 * 64 + lane];
            a4 += h[(size_t)c4 * 64 + lane];
            a5 += h[(size_t)c5 * 64 + lane];
            a6 += h[(size_t)c6 * 64 + lane];
            a7 += h[(size_t)c7 * 64 + lane];
        }
        for (; e < s1; ++e)
            a0 += h[(size_t)col[e] * 64 + lane];
        float aval = (((a0 + a1) + (a2 + a3)) + ((a4 + a5) + (a6 + a7))) + self;

        float s = b3s[lane];
#pragma unroll
        for (int i = 0; i < 64; ++i)
            s += __shfl(aval, i) * W3s[i * 64 + lane];
        float t = fmaxf(s, 0.f);

        float s2 = b4s[lane & 31];
#pragma unroll
        for (int j = 0; j < 64; ++j)
            s2 += __shfl(t, j) * W4s[j * 32 + (lane & 31)];
        if (lane < 32) out[(size_t)node * 32 + lane] = s2;
    }
}

extern "C" void kernel_launch(void* const* d_in, const int* in_sizes, int n_in,
                              void* d_out, int out_size, void* d_ws, size_t ws_size,
                              hipStream_t stream) {
    const float* x  = (const float*)d_in[0];
    const int*   ei = (const int*)d_in[1];
    const float* W1 = (const float*)d_in[2];
    const float* b1 = (const float*)d_in[3];
    const float* W2 = (const float*)d_in[4];
    const float* b2 = (const float*)d_in[5];
    const float* W3 = (const float*)d_in[6];
    const float* b3 = (const float*)d_in[7];
    const float* W4 = (const float*)d_in[8];
    const float* b4 = (const float*)d_in[9];
    float* out = (float*)d_out;

    char* ws = (char*)d_ws;
    float* h   = (float*)ws;                          ws += (size_t)NN * 64 * 4;       // 25.6 MB
    int*   col = (int*)ws;                            ws += (size_t)NE * 4;            // 6.4 MB
    int*   P   = (int*)ws;                            ws += (size_t)NN * NSP1 * 4;     // 5.6 MB

    // build-time arrays overlay the h region (dead before fused1 writes h)
    char* ov = (char*)h;
    int* deg2    = (int*)ov;                          ov += (size_t)NN * NS * 4;       // 5.2 MB
    int* deg     = (int*)ov;                          ov += (size_t)NN * 4;
    int* scanned = (int*)ov;                          ov += (size_t)NN * 4;
    int* bsums   = (int*)ov;                          ov += (size_t)NB * 4;

    // ---- slice-bucketed CSR build ----
    hipMemsetAsync(deg2, 0, (size_t)NN * NS * 4, stream);
    hist2_k<<<NE / 256, 256, 0, stream>>>(ei, deg2);
    rowsum_k<<<NB, 256, 0, stream>>>(deg2, deg);
    scan1_k<<<NB, 256, 0, stream>>>(deg, scanned, bsums);
    scan2_k<<<1, 512, 0, stream>>>(bsums);
    scan3b_k<<<NB, 256, 0, stream>>>(scanned, bsums, deg, deg2, P);
    fill2_k<<<NE / 256, 256, 0, stream>>>(ei, P, col);

    // ---- fused layers: reg-ILP gather over slice-sorted flat rows ----
    fused1<<<1536, 256, 0, stream>>>(x, P, col, W1, b1, W2, b2, h);
    fused2<<<1536, 256, 0, stream>>>(h, P, col, W3, b3, W4, b4, out);
}